// Round 3
// baseline (609.495 us; speedup 1.0000x reference)
//
#include <hip/hip_runtime.h>

#define LSEQ 1024
#define NDIM 256

// output layout (floats): c_all | y_all | GBT_A | GBT_B
#define O_C 0
#define O_Y (LSEQ * NDIM)                      // 262144
#define O_A (O_Y + LSEQ)                       // 263168
#define O_B (O_A + (size_t)LSEQ * NDIM * NDIM) // 67372032

typedef float v4f __attribute__((ext_vector_type(4)));

static __device__ __forceinline__ float frcp(float x) {
    return __builtin_amdgcn_rcpf(x);
}

__global__ __launch_bounds__(256) void hippo_main(
    const float* __restrict__ f,
    const float* __restrict__ init_state,
    const float* __restrict__ Bvec,   // = r_i = sqrt(2i+1), bit-exact vs reference
    float* __restrict__ out)
{
    const int tid = threadIdx.x;
    const int bid = blockIdx.x;

    if (bid == 0) {
        // ================= sequential scan: systolic over 64 lanes ==========
        // lane l owns elements i = 4l..4l+3. At tick t, lane l performs
        // recurrence step k0 = t - l. Scan state (T = prefix of r_j c_j,
        // S = forward-substitution prefix of r_j c_new_j, ssf = ss*f_k,
        // yacc = running row sum) flows lane -> lane+1 each tick.
        if (tid >= 64) return;
        const int l = tid;
        float rr[4], cc[4];
        #pragma unroll
        for (int e = 0; e < 4; ++e) {
            rr[e] = Bvec[4 * l + e];
            cc[e] = init_state[4 * l + e];
        }
        const float base1 = (float)(4 * l + 1);  // (i+1) for e=0

        float T = 0.0f, S = 0.0f, ssf = 0.0f, yacc = 0.0f;
        // f staged in 64-wide register chunks, rotated every 64 ticks
        float fcur = f[l];
        float fnxt = (64 + l < LSEQ) ? f[64 + l] : 0.0f;

        float* cout = out + O_C;
        float* yout = out + O_Y;

        for (int t = 0; t < LSEQ + 63; ++t) {
            if ((t & 63) == 0 && t) {
                fcur = fnxt;
                int idx = t + 64 + l;
                fnxt = (idx < LSEQ) ? f[idx] : 0.0f;
            }
            float Tn  = __shfl_up(T, 1);
            float Sn  = __shfl_up(S, 1);
            float ssn = __shfl_up(ssf, 1);
            float yn  = __shfl_up(yacc, 1);
            float ft  = __shfl(fcur, t & 63);   // uniform index -> readlane

            const int k0 = t - l;
            const float h = 0.5f * frcp((float)(k0 + 1));
            if (l == 0) {
                T = 0.0f; S = 0.0f; yacc = 0.0f;
                ssf = 2.0f * h * ft;            // ss * f[t]
            } else {
                T = Tn; S = Sn; yacc = yn; ssf = ssn;
            }

            if (k0 >= 0 && k0 < LSEQ) {
                #pragma unroll
                for (int e = 0; e < 4; ++e) {
                    float d    = fmaf(h, base1 + (float)e, 1.0f); // 1 + h(i+1)
                    float invd = frcp(d);
                    // w = (2-d)*c + r*(ssf - h*T)   [P2 row + forcing]
                    float w = fmaf(2.0f - d, cc[e], rr[e] * fmaf(-h, T, ssf));
                    T = fmaf(rr[e], cc[e], T);
                    // forward substitution: c_new = (w - h*r*S)/d
                    float num = fmaf(-h * rr[e], S, w);
                    float cn  = num * invd;
                    S = fmaf(rr[e], cn, S);
                    cc[e] = cn;
                }
                yacc += (cc[0] + cc[1]) + (cc[2] + cc[3]);
                v4f cv = { cc[0], cc[1], cc[2], cc[3] };
                *reinterpret_cast<v4f*>(cout + (size_t)k0 * NDIM + 4 * l) = cv;
                if (l == 63) yout[k0] = yacc;
            }
        }
    } else {
        // ================= GBT_A / GBT_B for k = bid-1 ======================
        // P1 = I - h A lower-triangular semiseparable; M = P1^{-1} has
        // M[i,i] = 1/d_i, M[i,j] = -h r_i r_j/(d_i d_j) * prod_{m=j+1}^{i-1} g_m,
        // g_m = (1 - h m)/d_m.  Ad = 2M - I.
        // 4 waves/block: wave w stores rows [64w, 64w+64); each wave runs the
        // (cheap) column-state recurrence redundantly up to its row range.
        const int k = bid - 1;
        const int lane = tid & 63;
        const int wave = tid >> 6;
        const float kp = (float)(k + 1);
        const float ss = 1.0f / kp;
        const float h  = 0.5f * ss;

        __shared__ float s_r[NDIM], s_invd[NDIM], s_rowco[NDIM], s_g[NDIM], s_diag[NDIM];
        {
            int i = tid;                           // 256 threads, 256 elements
            float r    = Bvec[i];
            float d    = fmaf(h, (float)(i + 1), 1.0f);
            float invd = 1.0f / d;
            s_r[i]     = r;
            s_invd[i]  = invd;
            s_rowco[i] = -2.0f * h * r * invd;     // 2 * (-h r_i / d_i)
            s_g[i]     = (1.0f - h * (float)i) * invd;
            s_diag[i]  = fmaf(2.0f, invd, -1.0f);  // 2/d_i - 1
        }
        __syncthreads();

        // lane owns columns j = 4*lane..4*lane+3; per-column running state
        float colc[4], Scol[4] = {0.f, 0.f, 0.f, 0.f};
        #pragma unroll
        for (int e = 0; e < 4; ++e) {
            int j = 4 * lane + e;
            colc[e] = s_r[j] * s_invd[j];          // start value when row passes j
        }

        const int i0 = wave * 64;
        // ---- recurrence-only rows [0, i0): advance column state, no stores
        for (int i = 0; i < i0; ++i) {
            float g = s_g[i];
            #pragma unroll
            for (int e = 0; e < 4; ++e) {
                int j = 4 * lane + e;
                if (j < i)       Scol[e] *= g;
                else if (j == i) Scol[e] = colc[e];
            }
        }
        // ---- owned rows [i0, i0+64): compute + nontemporal store
        float* outA = out + O_A + (size_t)k * (NDIM * NDIM) + 4 * lane;
        for (int i = i0; i < i0 + 64; ++i) {
            float rowco = s_rowco[i];
            float g     = s_g[i];
            float dg    = s_diag[i];
            float v[4];
            #pragma unroll
            for (int e = 0; e < 4; ++e) {
                int j = 4 * lane + e;
                if (j < i) {
                    v[e] = rowco * Scol[e];
                    Scol[e] *= g;
                } else if (j == i) {
                    v[e] = dg;
                    Scol[e] = colc[e];
                } else {
                    v[e] = 0.0f;
                }
            }
            v4f vv = { v[0], v[1], v[2], v[3] };
            __builtin_nontemporal_store(
                vv, reinterpret_cast<v4f*>(outA + (size_t)i * NDIM));
        }

        // GBT_B: Bd = ss * P1^{-1} r  via scalar forward substitution
        if (tid == 0) {
            float Sb = 0.0f;
            float* outB = out + O_B + (size_t)k * NDIM;
            for (int i = 0; i < NDIM; ++i) {
                float x = s_r[i] * (ss - h * Sb) * s_invd[i];
                outB[i] = x;
                Sb = fmaf(s_r[i], x, Sb);
            }
        }
    }
}

extern "C" void kernel_launch(void* const* d_in, const int* in_sizes, int n_in,
                              void* d_out, int out_size, void* d_ws, size_t ws_size,
                              hipStream_t stream) {
    (void)in_sizes; (void)n_in; (void)d_ws; (void)ws_size; (void)out_size;
    const float* f    = (const float*)d_in[0];
    const float* init = (const float*)d_in[1];
    const float* Bv   = (const float*)d_in[3];   // B = r[:,None]
    float* outp       = (float*)d_out;
    hippo_main<<<1 + LSEQ, 256, 0, stream>>>(f, init, Bv, outp);
}

// Round 4
// 574.630 us; speedup vs baseline: 1.0607x; 1.0607x over previous
//
#include <hip/hip_runtime.h>

#define LSEQ 1024
#define NDIM 256

// output layout (floats): c_all | y_all | GBT_A | GBT_B
#define O_C 0
#define O_Y (LSEQ * NDIM)                      // 262144
#define O_A (O_Y + LSEQ)                       // 263168
#define O_B (O_A + (size_t)LSEQ * NDIM * NDIM) // 67372032

typedef float v4f __attribute__((ext_vector_type(4)));

static __device__ __forceinline__ float frcp(float x) {
    return __builtin_amdgcn_rcpf(x);
}

// wave-wide shift-right-by-1 via DPP (VALU, no DS pipe).
// lane l gets src from lane l-1; lane 0 gets `inject`.
static __device__ __forceinline__ float dpp_shr1(float inject, float src) {
    int r = __builtin_amdgcn_update_dpp(
        __float_as_int(inject), __float_as_int(src),
        0x138 /* WAVE_SHR1 */, 0xF, 0xF, false);
    return __int_as_float(r);
}

__global__ __launch_bounds__(256) void hippo_main(
    const float* __restrict__ f,
    const float* __restrict__ init_state,
    const float* __restrict__ Bvec,   // = r_i = sqrt(2i+1), bit-exact vs reference
    float* __restrict__ out)
{
    const int tid = threadIdx.x;
    const int bid = blockIdx.x;

    if (bid == 0) {
        // ================= sequential scan: systolic over 64 lanes ==========
        // lane l owns elements i = 4l..4l+3. At tick t, lane l performs
        // recurrence step k0 = t - l. Scan state (T = prefix of r_j c_j,
        // S = forward-substitution prefix of r_j c_new_j, ssf = ss*f_k,
        // yacc = running row sum) flows lane -> lane+1 each tick via DPP
        // wave_shr1 (VALU-speed; __shfl_up's ds_bpermute latency was the
        // 400 us critical path in R1/R3).
        if (tid >= 64) return;
        const int l = tid;
        float rr[4], cc[4];
        #pragma unroll
        for (int e = 0; e < 4; ++e) {
            rr[e] = Bvec[4 * l + e];
            cc[e] = init_state[4 * l + e];
        }
        const float base1 = (float)(4 * l + 1);  // (i+1) for e=0

        float T = 0.0f, S = 0.0f, ssf = 0.0f, yacc = 0.0f;
        // f staged in 64-wide register chunks, rotated every 64 ticks
        float fcur = f[l];
        float fnxt = (64 + l < LSEQ) ? f[64 + l] : 0.0f;

        float* cout = out + O_C;
        float* yout = out + O_Y;

        for (int t = 0; t < LSEQ + 63; ++t) {
            if ((t & 63) == 0 && t) {
                fcur = fnxt;
                int idx = t + 64 + l;
                fnxt = (idx < LSEQ) ? f[idx] : 0.0f;
            }
            // f[t] broadcast: uniform lane index -> scalar readlane (no DS)
            float ft = __int_as_float(
                __builtin_amdgcn_readlane(__float_as_int(fcur), t & 63));

            const int k0 = t - l;
            const float h  = 0.5f * frcp((float)(k0 + 1));   // lane's ss/2
            const float h0 = 0.5f * frcp((float)(t + 1));    // lane 0's ss/2
            const float ssf0 = 2.0f * h0 * ft;               // ss_t * f_t

            // pipeline handoff (unconditional, all 64 lanes active)
            T    = dpp_shr1(0.0f, T);
            S    = dpp_shr1(0.0f, S);
            yacc = dpp_shr1(0.0f, yacc);
            ssf  = dpp_shr1(ssf0, ssf);

            if (k0 >= 0 && k0 < LSEQ) {
                #pragma unroll
                for (int e = 0; e < 4; ++e) {
                    float d    = fmaf(h, base1 + (float)e, 1.0f); // 1 + h(i+1)
                    float invd = frcp(d);
                    // w = (2-d)*c + r*(ssf - h*T)   [P2 row + forcing]
                    float w = fmaf(2.0f - d, cc[e], rr[e] * fmaf(-h, T, ssf));
                    T = fmaf(rr[e], cc[e], T);
                    // forward substitution: c_new = (w - h*r*S)/d
                    float num = fmaf(-h * rr[e], S, w);
                    float cn  = num * invd;
                    S = fmaf(rr[e], cn, S);
                    cc[e] = cn;
                }
                yacc += (cc[0] + cc[1]) + (cc[2] + cc[3]);
                v4f cv = { cc[0], cc[1], cc[2], cc[3] };
                *reinterpret_cast<v4f*>(cout + (size_t)k0 * NDIM + 4 * l) = cv;
                if (l == 63) yout[k0] = yacc;
            }
        }
    } else {
        // ================= GBT_A / GBT_B for k = bid-1 ======================
        // P1 = I - h A lower-triangular semiseparable; M = P1^{-1} has
        // M[i,i] = 1/d_i, M[i,j] = -h r_i r_j/(d_i d_j) * prod_{m=j+1}^{i-1} g_m,
        // g_m = (1 - h m)/d_m.  Ad = 2M - I.
        // 4 waves/block: wave w stores rows [64w, 64w+64); each wave runs the
        // (cheap) column-state recurrence redundantly up to its row range.
        const int k = bid - 1;
        const int lane = tid & 63;
        const int wave = tid >> 6;
        const float kp = (float)(k + 1);
        const float ss = 1.0f / kp;
        const float h  = 0.5f * ss;

        __shared__ float s_r[NDIM], s_invd[NDIM], s_rowco[NDIM], s_g[NDIM], s_diag[NDIM];
        {
            int i = tid;                           // 256 threads, 256 elements
            float r    = Bvec[i];
            float d    = fmaf(h, (float)(i + 1), 1.0f);
            float invd = 1.0f / d;
            s_r[i]     = r;
            s_invd[i]  = invd;
            s_rowco[i] = -2.0f * h * r * invd;     // 2 * (-h r_i / d_i)
            s_g[i]     = (1.0f - h * (float)i) * invd;
            s_diag[i]  = fmaf(2.0f, invd, -1.0f);  // 2/d_i - 1
        }
        __syncthreads();

        // lane owns columns j = 4*lane..4*lane+3; per-column running state
        float colc[4], Scol[4] = {0.f, 0.f, 0.f, 0.f};
        #pragma unroll
        for (int e = 0; e < 4; ++e) {
            int j = 4 * lane + e;
            colc[e] = s_r[j] * s_invd[j];          // start value when row passes j
        }

        const int i0 = wave * 64;
        // ---- recurrence-only rows [0, i0): advance column state, no stores
        for (int i = 0; i < i0; ++i) {
            float g = s_g[i];
            #pragma unroll
            for (int e = 0; e < 4; ++e) {
                int j = 4 * lane + e;
                if (j < i)       Scol[e] *= g;
                else if (j == i) Scol[e] = colc[e];
            }
        }
        // ---- owned rows [i0, i0+64): compute + nontemporal store
        float* outA = out + O_A + (size_t)k * (NDIM * NDIM) + 4 * lane;
        for (int i = i0; i < i0 + 64; ++i) {
            float rowco = s_rowco[i];
            float g     = s_g[i];
            float dg    = s_diag[i];
            float v[4];
            #pragma unroll
            for (int e = 0; e < 4; ++e) {
                int j = 4 * lane + e;
                if (j < i) {
                    v[e] = rowco * Scol[e];
                    Scol[e] *= g;
                } else if (j == i) {
                    v[e] = dg;
                    Scol[e] = colc[e];
                } else {
                    v[e] = 0.0f;
                }
            }
            v4f vv = { v[0], v[1], v[2], v[3] };
            __builtin_nontemporal_store(
                vv, reinterpret_cast<v4f*>(outA + (size_t)i * NDIM));
        }

        // GBT_B: Bd = ss * P1^{-1} r  via scalar forward substitution
        if (tid == 0) {
            float Sb = 0.0f;
            float* outB = out + O_B + (size_t)k * NDIM;
            for (int i = 0; i < NDIM; ++i) {
                float x = s_r[i] * (ss - h * Sb) * s_invd[i];
                outB[i] = x;
                Sb = fmaf(s_r[i], x, Sb);
            }
        }
    }
}

extern "C" void kernel_launch(void* const* d_in, const int* in_sizes, int n_in,
                              void* d_out, int out_size, void* d_ws, size_t ws_size,
                              hipStream_t stream) {
    (void)in_sizes; (void)n_in; (void)d_ws; (void)ws_size; (void)out_size;
    const float* f    = (const float*)d_in[0];
    const float* init = (const float*)d_in[1];
    const float* Bv   = (const float*)d_in[3];   // B = r[:,None]
    float* outp       = (float*)d_out;
    hippo_main<<<1 + LSEQ, 256, 0, stream>>>(f, init, Bv, outp);
}